// Round 9
// baseline (123.773 us; speedup 1.0000x reference)
//
#include <hip/hip_runtime.h>

// MountainCar batched rollout: B=8192 envs, 500 sequential steps of a
// 2->64->1 MLP policy + dynamics.
//
// Round 9 = PACKED-PAIR: 2 envs per thread, one in each half of v2f state.
// R5 showed the compiler serializes two scalar env chains; R8 showed
// v_pk_*_f32 is ~full-rate. Packing envs into pk-op halves makes the
// 2-way interleave structural (encoding-enforced), halving per-env MLP
// issue and amortizing loop/ballot overhead, while scalar pairs
// (cos/exp2/rcp x2) provide natural ILP for trans latency.
// KL=16 lanes/env-pair, 65536 threads = 1024 waves = 1/SIMD.
// Kept from R7: write-at-crossing (no per-step state merges), intrinsic
// DPP butterfly, sign-free tanh, b2 seed on lane 0, deferred -0.1 reward.

typedef float v2f __attribute__((ext_vector_type(2)));

constexpr int B = 8192;
constexpr int L = 64;
constexpr int MAX_STEPS = 500;
constexpr float GOAL_P = 0.5f;
constexpr float MIN_P  = -1.2f;
constexpr float MIN_V  = -0.07f;
constexpr float MAX_V  = 0.07f;

constexpr int KL  = 16;       // lanes per env-pair
constexpr int UPL = L / KL;   // hidden units per lane = 4
constexpr int EPT = 2;        // envs per thread (v2f halves)

// Packed butterfly stage: x += x_from_lane(CTRL), both halves.
template<int CTRL>
__device__ __forceinline__ v2f dpp_add2(v2f x) {
  int yx = __builtin_amdgcn_update_dpp(0, __float_as_int(x.x), CTRL, 0xf, 0xf, true);
  int yy = __builtin_amdgcn_update_dpp(0, __float_as_int(x.y), CTRL, 0xf, 0xf, true);
  return x + (v2f){__int_as_float(yx), __int_as_float(yy)};
}

__global__ __launch_bounds__(256, 1) void mc_kernel(
    const float* __restrict__ x,  const float* __restrict__ w1,
    const float* __restrict__ b1, const float* __restrict__ w2,
    const float* __restrict__ b2, float* __restrict__ out)
{
  int tid  = blockIdx.x * blockDim.x + threadIdx.x;
  int grp  = tid >> 4;                 // env-pair index (envs 2g, 2g+1)
  int sub  = tid & 15;                 // lane-within-group
  int lane = threadIdx.x & 63;         // lane-within-wave

  constexpr float TS = 2.8853900817779268f;  // 2*log2(e), folded into w2/b2

  // Weights broadcast to both halves (loop-invariant v2f pairs in VGPRs).
  v2f W1A[UPL], W1B[UPL], B1R[UPL], W2R[UPL];
  const int j0 = sub * UPL;
#pragma unroll
  for (int i = 0; i < UPL; ++i) {
    float a = w1[j0 + i], b = w1[L + j0 + i], c = b1[j0 + i],
          d = w2[j0 + i] * TS;
    W1A[i] = (v2f){a, a};
    W1B[i] = (v2f){b, b};
    B1R[i] = (v2f){c, c};
    W2R[i] = (v2f){d, d};
  }
  const float bseed = (sub == 0) ? b2[0] * TS : 0.0f;
  const v2f sv0 = {bseed, bseed};   // b2 seed for both envs, lane 0 only

  float4 st0 = reinterpret_cast<const float4*>(x)[grp * EPT + 0];
  float4 st1 = reinterpret_cast<const float4*>(x)[grp * EPT + 1];
  v2f p = {st0.x, st1.x}, v = {st0.y, st1.y}, u = {st0.z, st1.z};
  const v2f r0 = {st0.w, st1.w};
  v2f racc = {0.0f, 0.0f};

  unsigned long long live0 = __ballot(true);
  unsigned long long live1 = live0;

  for (int stp = 0; stp < MAX_STEPS; ++stp) {
    v2f p1 = __builtin_elementwise_max(p, (v2f){MIN_P, MIN_P});
    v2f v1 = { (p.x <= MIN_P) ? 0.0f : v.x,
               (p.y <= MIN_P) ? 0.0f : v.y };

    // cos(3*p1) per env (v_cos, revolutions) — independent pair, issued
    // early so trans latency hides under the MLP chain.
    float c0 = __builtin_amdgcn_cosf(p1.x * 0.47746482927568601f);
    float c1 = __builtin_amdgcn_cosf(p1.y * 0.47746482927568601f);

    // MLP: both envs per pk instruction. 4 units/lane, seeded with b2.
    v2f s = sv0;
#pragma unroll
    for (int i = 0; i < UPL; ++i) {
      v2f h = __builtin_elementwise_fma(v1, W1B[i],
              __builtin_elementwise_fma(p1, W1A[i], B1R[i]));
      h = __builtin_elementwise_max(h, (v2f){0.0f, 0.0f});
      s = __builtin_elementwise_fma(h, W2R[i], s);
    }

    // 16-lane butterfly, both halves; all lanes end with both full logits.
    s = dpp_add2<0xB1>(s);     // + lane^1
    s = dpp_add2<0x4E>(s);     // + lane^2
    s = dpp_add2<0x141>(s);    // + lane^(4..7)  (row_half_mirror)
    s = dpp_add2<0x140>(s);    // + lane^(8..15) (row_mirror)

    // tanh, sign-free: 1 - 2/(exp2(s)+1); independent scalar pair.
    float e0 = __builtin_amdgcn_exp2f(s.x);
    float e1 = __builtin_amdgcn_exp2f(s.y);
    float q0 = __builtin_amdgcn_rcpf(e0 + 1.0f);
    float q1 = __builtin_amdgcn_rcpf(e1 + 1.0f);
    v2f u1 = { fmaf(-2.0f, q0, 1.0f), fmaf(-2.0f, q1, 1.0f) };

    v2f vc = __builtin_elementwise_fma((v2f){-0.0025f, -0.0025f}, (v2f){c0, c1},
             __builtin_elementwise_fma((v2f){0.0015f, 0.0015f}, u1, v1));
    v2f v2c = { __builtin_amdgcn_fmed3f(vc.x, MIN_V, MAX_V),
                __builtin_amdgcn_fmed3f(vc.y, MIN_V, MAX_V) };

    // Unconditional state update (write-at-crossing, no merges).
    p = p1 + v2c;
    v = v2c;
    u = u1;
    racc = __builtin_elementwise_fma(u1, u1, racc);

    // Newly-crossed envs commit their final row immediately.
    unsigned long long c0m = __ballot(p.x > GOAL_P) & live0;
    unsigned long long c1m = __ballot(p.y > GOAL_P) & live1;
    if (c0m | c1m) {                      // wave-uniform, rarely taken
      live0 &= ~c0m;
      live1 &= ~c1m;
      if (((c0m >> lane) & 1ull) && sub == 0) {
        float rout = fmaf(-0.1f, racc.x, r0.x) + 100.0f;
        reinterpret_cast<float4*>(out)[grp * EPT + 0] =
            make_float4(p.x, v.x, u.x, rout);
      }
      if (((c1m >> lane) & 1ull) && sub == 0) {
        float rout = fmaf(-0.1f, racc.y, r0.y) + 100.0f;
        reinterpret_cast<float4*>(out)[grp * EPT + 1] =
            make_float4(p.y, v.y, u.y, rout);
      }
      if (!(live0 | live1)) return;
    }
  }

  // Envs that never crossed within MAX_STEPS: no +100.
  if (sub == 0) {
    if ((live0 >> lane) & 1ull) {
      float rout = fmaf(-0.1f, racc.x, r0.x);
      reinterpret_cast<float4*>(out)[grp * EPT + 0] =
          make_float4(p.x, v.x, u.x, rout);
    }
    if ((live1 >> lane) & 1ull) {
      float rout = fmaf(-0.1f, racc.y, r0.y);
      reinterpret_cast<float4*>(out)[grp * EPT + 1] =
          make_float4(p.y, v.y, u.y, rout);
    }
  }
}

extern "C" void kernel_launch(void* const* d_in, const int* in_sizes, int n_in,
                              void* d_out, int out_size, void* d_ws, size_t ws_size,
                              hipStream_t stream) {
  const float* x  = (const float*)d_in[0];
  const float* w1 = (const float*)d_in[1];
  const float* b1 = (const float*)d_in[2];
  const float* w2 = (const float*)d_in[3];
  const float* b2 = (const float*)d_in[4];
  float* out = (float*)d_out;

  constexpr int threads = (B / EPT) * KL;  // 65536 -> 1024 waves -> 1/SIMD
  mc_kernel<<<threads / 256, 256, 0, stream>>>(x, w1, b1, w2, b2, out);
}